// Round 3
// baseline (392.058 us; speedup 1.0000x reference)
//
#include <hip/hip_runtime.h>

// DecoupledMoE: out[b,o,p] = sum_i (W_shared[o,i] + w[b]*W_routed[e_b,o,i]) * x[b,i,p]
//                            + (b_shared[o] + w[b]*b_routed[e_b,o])
// B=128, C_IN=C_OUT=64, HW=3136 (fp32). fp32 VALU floor ~22us.
// R2 post-mortem: VALU work correct (~28us busy-time) but 55% stalled on x loads
// (no regs to pipeline) and x re-read 8x through L1/L2.
// R3: OT=16,TP=4 (acc=64 VGPR, block covers all 64 out-ch -> x re-read 4x) +
// explicit 2-deep load pipeline with named buffers.

#define HW     3136
#define CIN    64
#define COUT   64
#define CHUNK  256   // pixels per block (64 float4)
#define OT     16    // out channels per wave; 4 waves -> all 64
#define NCHUNK 13    // ceil(3136/256); last chunk overlaps (rewrites same values)

__global__ __launch_bounds__(256, 4) void moe_fused(
    const float* __restrict__ x,
    const float* __restrict__ weights,
    const int*   __restrict__ indices,
    const float* __restrict__ W_shared,
    const float* __restrict__ b_shared,
    const float* __restrict__ W_routed,
    const float* __restrict__ b_routed,
    float* __restrict__ out)
{
    __shared__ float Wl[COUT * CIN];   // fused per-sample weight, 16 KB
    __shared__ float bl[COUT];

    const int bid   = blockIdx.x;
    const int b     = bid >> 4;                  // sample = bid / 13 via layout below
    // grid.x = 128 * 13; decode without div: use y for sample instead
    const int chunk = bid;                       // (unused placeholder, see launch)

    // -- decoded via 2D grid: blockIdx.x = chunk, blockIdx.y = sample --
    const int bs = blockIdx.y;
    int c0 = blockIdx.x * CHUNK;
    if (c0 > HW - CHUNK) c0 = HW - CHUNK;        // overlap region: same values twice

    const float wb = weights[bs];
    const int   e  = indices[bs];

    // Stage fused weight into LDS (coalesced, once per block)
    const float* __restrict__ Wrp = W_routed + (size_t)e * (COUT * CIN);
    #pragma unroll
    for (int k = 0; k < 16; ++k) {
        const int idx = threadIdx.x + k * 256;
        Wl[idx] = W_shared[idx] + wb * Wrp[idx];
    }
    if (threadIdx.x < COUT)
        bl[threadIdx.x] = b_shared[threadIdx.x]
                        + wb * b_routed[e * COUT + threadIdx.x];
    __syncthreads();

    const int wave = threadIdx.x >> 6;
    const int lane = threadIdx.x & 63;
    const int ob   = wave * OT;                  // this wave's 16 out-channels

    // lane owns float4 #lane of the 64-float4 chunk (dense 1KB/wave-instr)
    const float* __restrict__ xb = x + (size_t)bs * CIN * HW + c0 + 4 * lane;

    float acc[OT][4];
    #pragma unroll
    for (int o = 0; o < OT; ++o) {
        acc[o][0] = 0.f; acc[o][1] = 0.f; acc[o][2] = 0.f; acc[o][3] = 0.f;
    }

    // ---- 2-deep pipelined K loop over 16 channel-groups of 4 ----
    float4 xvA[4], xvB[4];

    #pragma unroll
    for (int di = 0; di < 4; ++di)
        xvA[di] = *(const float4*)(xb + (size_t)di * HW);

    #pragma unroll
    for (int ib = 0; ib < 16; ib += 2) {
        // prefetch group ib+1 while computing group ib
        #pragma unroll
        for (int di = 0; di < 4; ++di)
            xvB[di] = *(const float4*)(xb + (size_t)((ib + 1) * 4 + di) * HW);

        #pragma unroll
        for (int o = 0; o < OT; ++o) {
            const float4 wv = *(const float4*)&Wl[(ob + o) * CIN + ib * 4];
            #pragma unroll
            for (int di = 0; di < 4; ++di) {
                const float w = (&wv.x)[di];
                acc[o][0] += w * xvA[di].x;
                acc[o][1] += w * xvA[di].y;
                acc[o][2] += w * xvA[di].z;
                acc[o][3] += w * xvA[di].w;
            }
        }

        // prefetch group ib+2 while computing group ib+1 (guard the tail)
        if (ib + 2 < 16) {
            #pragma unroll
            for (int di = 0; di < 4; ++di)
                xvA[di] = *(const float4*)(xb + (size_t)((ib + 2) * 4 + di) * HW);
        }

        #pragma unroll
        for (int o = 0; o < OT; ++o) {
            const float4 wv = *(const float4*)&Wl[(ob + o) * CIN + (ib + 1) * 4];
            #pragma unroll
            for (int di = 0; di < 4; ++di) {
                const float w = (&wv.x)[di];
                acc[o][0] += w * xvB[di].x;
                acc[o][1] += w * xvB[di].y;
                acc[o][2] += w * xvB[di].z;
                acc[o][3] += w * xvB[di].w;
            }
        }
    }

    // Epilogue: fused bias, dense float4 stores (one per out-channel)
    float* __restrict__ op_base = out + (size_t)bs * COUT * HW + c0 + 4 * lane;
    #pragma unroll
    for (int o = 0; o < OT; ++o) {
        const float be = bl[ob + o];
        float4 r = make_float4(acc[o][0] + be, acc[o][1] + be,
                               acc[o][2] + be, acc[o][3] + be);
        *(float4*)(op_base + (size_t)(ob + o) * HW) = r;
    }
}

extern "C" void kernel_launch(void* const* d_in, const int* in_sizes, int n_in,
                              void* d_out, int out_size, void* d_ws, size_t ws_size,
                              hipStream_t stream) {
    const float* x        = (const float*)d_in[0];
    const float* weights  = (const float*)d_in[1];
    const int*   indices  = (const int*)  d_in[2];
    const float* W_shared = (const float*)d_in[3];
    const float* b_shared = (const float*)d_in[4];
    const float* W_routed = (const float*)d_in[5];
    const float* b_routed = (const float*)d_in[6];
    float* out = (float*)d_out;

    // grid: 13 pixel-chunks x 128 samples; each block does all 64 out-channels
    moe_fused<<<dim3(NCHUNK, 128), 256, 0, stream>>>(
        x, weights, indices, W_shared, b_shared, W_routed, b_routed, out);
}

// Round 4
// 268.438 us; speedup vs baseline: 1.4605x; 1.4605x over previous
//
#include <hip/hip_runtime.h>

// DecoupledMoE: out[b,o,p] = sum_i (W_shared[o,i] + w[b]*W_routed[e_b,o,i]) * x[b,i,p]
//                            + (b_shared[o] + w[b]*b_routed[e_b,o])
// B=128, C_IN=C_OUT=64, HW=3136 (fp32).
// R3 post-mortem: full-unroll K-loop + 128-VGPR cap -> scratch spills
// (FETCH 745MB / WRITE 671MB, VALU 12%). R4: same geometry, runtime K-loop
// (unroll 1, peeled tail) + launch_bounds(256,3) (~168 VGPR cap, no spill).

#define HW     3136
#define CIN    64
#define COUT   64
#define CHUNK  256   // pixels per block (64 float4)
#define OT     16    // out channels per wave; 4 waves -> all 64
#define NCHUNK 13    // ceil(3136/256); last chunk overlaps (rewrites same values)

#define COMPUTE_GROUP(XV, IBASE)                                        \
    do {                                                                \
        _Pragma("unroll")                                               \
        for (int o = 0; o < OT; ++o) {                                  \
            const float4 wv = *(const float4*)&Wl[(ob + o) * CIN + (IBASE) * 4]; \
            _Pragma("unroll")                                           \
            for (int di = 0; di < 4; ++di) {                            \
                const float w = (&wv.x)[di];                            \
                acc[o][0] += w * XV[di].x;                              \
                acc[o][1] += w * XV[di].y;                              \
                acc[o][2] += w * XV[di].z;                              \
                acc[o][3] += w * XV[di].w;                              \
            }                                                           \
        }                                                               \
    } while (0)

#define LOAD_GROUP(XV, IBASE)                                           \
    do {                                                                \
        _Pragma("unroll")                                               \
        for (int di = 0; di < 4; ++di)                                  \
            XV[di] = *(const float4*)(xb + (size_t)((IBASE) * 4 + di) * HW); \
    } while (0)

__global__ __launch_bounds__(256, 3) void moe_fused(
    const float* __restrict__ x,
    const float* __restrict__ weights,
    const int*   __restrict__ indices,
    const float* __restrict__ W_shared,
    const float* __restrict__ b_shared,
    const float* __restrict__ W_routed,
    const float* __restrict__ b_routed,
    float* __restrict__ out)
{
    __shared__ float Wl[COUT * CIN];   // fused per-sample weight, 16 KB
    __shared__ float bl[COUT];

    const int bs = blockIdx.y;                   // sample
    int c0 = blockIdx.x * CHUNK;                 // pixel chunk
    if (c0 > HW - CHUNK) c0 = HW - CHUNK;        // overlap region: same values twice

    const float wb = weights[bs];
    const int   e  = indices[bs];

    // Stage fused weight into LDS (coalesced, once per block)
    const float* __restrict__ Wrp = W_routed + (size_t)e * (COUT * CIN);
    #pragma unroll
    for (int k = 0; k < 16; ++k) {
        const int idx = threadIdx.x + k * 256;
        Wl[idx] = W_shared[idx] + wb * Wrp[idx];
    }
    if (threadIdx.x < COUT)
        bl[threadIdx.x] = b_shared[threadIdx.x]
                        + wb * b_routed[e * COUT + threadIdx.x];
    __syncthreads();

    const int wave = threadIdx.x >> 6;
    const int lane = threadIdx.x & 63;
    const int ob   = wave * OT;                  // this wave's 16 out-channels

    // lane owns float4 #lane of the 64-float4 chunk (dense 1KB/wave-instr)
    const float* __restrict__ xb = x + (size_t)bs * CIN * HW + c0 + 4 * lane;

    float acc[OT][4];
    #pragma unroll
    for (int o = 0; o < OT; ++o) {
        acc[o][0] = 0.f; acc[o][1] = 0.f; acc[o][2] = 0.f; acc[o][3] = 0.f;
    }

    // ---- 2-deep pipelined K loop, runtime trip count (NO full unroll) ----
    float4 xvA[4], xvB[4];
    LOAD_GROUP(xvA, 0);

    #pragma unroll 1
    for (int ib = 0; ib < 14; ib += 2) {
        LOAD_GROUP(xvB, ib + 1);        // prefetch next group
        COMPUTE_GROUP(xvA, ib);         // compute current (hides B-load latency)
        LOAD_GROUP(xvA, ib + 2);        // prefetch group after
        COMPUTE_GROUP(xvB, ib + 1);
    }
    // peeled tail: groups 14, 15
    LOAD_GROUP(xvB, 15);
    COMPUTE_GROUP(xvA, 14);
    COMPUTE_GROUP(xvB, 15);

    // Epilogue: fused bias, dense float4 stores (one per out-channel)
    float* __restrict__ op_base = out + (size_t)bs * COUT * HW + c0 + 4 * lane;
    #pragma unroll
    for (int o = 0; o < OT; ++o) {
        const float be = bl[ob + o];
        float4 r = make_float4(acc[o][0] + be, acc[o][1] + be,
                               acc[o][2] + be, acc[o][3] + be);
        *(float4*)(op_base + (size_t)(ob + o) * HW) = r;
    }
}

extern "C" void kernel_launch(void* const* d_in, const int* in_sizes, int n_in,
                              void* d_out, int out_size, void* d_ws, size_t ws_size,
                              hipStream_t stream) {
    const float* x        = (const float*)d_in[0];
    const float* weights  = (const float*)d_in[1];
    const int*   indices  = (const int*)  d_in[2];
    const float* W_shared = (const float*)d_in[3];
    const float* b_shared = (const float*)d_in[4];
    const float* W_routed = (const float*)d_in[5];
    const float* b_routed = (const float*)d_in[6];
    float* out = (float*)d_out;

    // grid: 13 pixel-chunks x 128 samples; each block does all 64 out-channels
    moe_fused<<<dim3(NCHUNK, 128), 256, 0, stream>>>(
        x, weights, indices, W_shared, b_shared, W_routed, b_routed, out);
}

// Round 5
// 45.005 us; speedup vs baseline: 8.7115x; 5.9647x over previous
//
#include <hip/hip_runtime.h>

// DecoupledMoE: out[b,o,p] = sum_i (W_shared[o,i] + w[b]*W_routed[e_b,o,i]) * x[b,i,p]
//                            + (b_shared[o] + w[b]*b_routed[e_b,o])
// B=128, C_IN=C_OUT=64, HW=3136, fp32 I/O. Threshold 8.56e-2 = 8 bf16-ulps ->
// bf16 MFMA sanctioned. R5: mfma_f32_32x32x16_bf16, no LDS, no barriers.
// Wave = 32 out-ch x 128 px (4 tiles); block = 4 waves (2 o-tiles x 256 px).
// fp32 R2-R4 were VALU/spill-bound; MFMA cuts FMA time 21us -> 1.6us.

typedef __bf16 bf16x8 __attribute__((ext_vector_type(8)));
typedef float  f32x16 __attribute__((ext_vector_type(16)));

#define HW     3136
#define CIN    64
#define COUT   64
#define NTILES 98     // 3136 / 32 pixel-tiles
#define NGRP   13     // groups of 8 tiles; last group overlaps (rewrites same values)

__global__ __launch_bounds__(256, 4) void moe_mfma(
    const float* __restrict__ x,
    const float* __restrict__ weights,
    const int*   __restrict__ indices,
    const float* __restrict__ W_shared,
    const float* __restrict__ b_shared,
    const float* __restrict__ W_routed,
    const float* __restrict__ b_routed,
    float* __restrict__ out)
{
    const int bs   = blockIdx.y;          // sample
    const int wave = threadIdx.x >> 6;
    const int lane = threadIdx.x & 63;
    const int l5   = lane >> 5;           // 0/1 half-wave group
    const int l31  = lane & 31;

    const float wb = weights[bs];
    const int   e  = indices[bs];
    const int   ob = (wave >> 1) * 32;    // o-tile base (0 or 32)

    int tile0 = blockIdx.x * 8;
    if (tile0 > NTILES - 8) tile0 = NTILES - 8;   // overlap trick, deterministic
    const int px0 = (tile0 + (wave & 1) * 4) * 32;

    // ---- A fragments: W_eff[ob + l31][k], k = 16*ks + 8*l5 + j  (j=0..7) ----
    bf16x8 afrag[4];
    {
        const float* Ws = W_shared + (size_t)(ob + l31) * CIN + 8 * l5;
        const float* Wr = W_routed + ((size_t)e * COUT + ob + l31) * CIN + 8 * l5;
        #pragma unroll
        for (int ks = 0; ks < 4; ++ks) {
            float4 s0 = *(const float4*)(Ws + 16 * ks);
            float4 s1 = *(const float4*)(Ws + 16 * ks + 4);
            float4 r0 = *(const float4*)(Wr + 16 * ks);
            float4 r1 = *(const float4*)(Wr + 16 * ks + 4);
            float t[8];
            t[0] = s0.x + wb * r0.x;  t[1] = s0.y + wb * r0.y;
            t[2] = s0.z + wb * r0.z;  t[3] = s0.w + wb * r0.w;
            t[4] = s1.x + wb * r1.x;  t[5] = s1.y + wb * r1.y;
            t[6] = s1.z + wb * r1.z;  t[7] = s1.w + wb * r1.w;
            #pragma unroll
            for (int j = 0; j < 8; ++j) afrag[ks][j] = (__bf16)t[j];
        }
    }

    // ---- fused bias as accumulator init: reg r <-> row (r&3)+8*(r>>2)+4*l5 ----
    f32x16 biasv;
    #pragma unroll
    for (int g = 0; g < 4; ++g) {
        const int o4 = ob + 8 * g + 4 * l5;
        float4 s = *(const float4*)(b_shared + o4);
        float4 r = *(const float4*)(b_routed + e * COUT + o4);
        biasv[4 * g + 0] = s.x + wb * r.x;
        biasv[4 * g + 1] = s.y + wb * r.y;
        biasv[4 * g + 2] = s.z + wb * r.z;
        biasv[4 * g + 3] = s.w + wb * r.w;
    }

    const float* __restrict__ xs = x   + (size_t)bs * CIN  * HW;
    float*       __restrict__ os = out + (size_t)bs * COUT * HW;

    #pragma unroll 1
    for (int t = 0; t < 4; ++t) {
        const int px = px0 + t * 32 + l31;
        f32x16 acc = biasv;
        #pragma unroll
        for (int ks = 0; ks < 4; ++ks) {
            // B fragment: x[16*ks + 8*l5 + j][px]  (lanes 0-31 = 128B segments)
            const float* xp = xs + (size_t)(16 * ks + 8 * l5) * HW + px;
            float xv[8];
            #pragma unroll
            for (int j = 0; j < 8; ++j) xv[j] = xp[(size_t)j * HW];
            bf16x8 bfr;
            #pragma unroll
            for (int j = 0; j < 8; ++j) bfr[j] = (__bf16)xv[j];
            acc = __builtin_amdgcn_mfma_f32_32x32x16_bf16(afrag[ks], bfr, acc, 0, 0, 0);
        }
        // C store: verified layout col=l31, row=(r&3)+8*(r>>2)+4*l5
        #pragma unroll
        for (int r = 0; r < 16; ++r) {
            const int row = ob + (r & 3) + 8 * (r >> 2) + 4 * l5;
            os[(size_t)row * HW + px] = acc[r];
        }
    }
}

extern "C" void kernel_launch(void* const* d_in, const int* in_sizes, int n_in,
                              void* d_out, int out_size, void* d_ws, size_t ws_size,
                              hipStream_t stream) {
    const float* x        = (const float*)d_in[0];
    const float* weights  = (const float*)d_in[1];
    const int*   indices  = (const int*)  d_in[2];
    const float* W_shared = (const float*)d_in[3];
    const float* b_shared = (const float*)d_in[4];
    const float* W_routed = (const float*)d_in[5];
    const float* b_routed = (const float*)d_in[6];
    float* out = (float*)d_out;

    // 13 tile-groups x 128 samples; block = 4 waves = 2 o-tiles x 8 px-tiles
    moe_mfma<<<dim3(NGRP, 128), 256, 0, stream>>>(
        x, weights, indices, W_shared, b_shared, W_routed, b_routed, out);
}

// Round 6
// 44.860 us; speedup vs baseline: 8.7395x; 1.0032x over previous
//
#include <hip/hip_runtime.h>

// DecoupledMoE: out[b,o,p] = sum_i (W_shared[o,i] + w[b]*W_routed[e_b,o,i]) * x[b,i,p]
//                            + (b_shared[o] + w[b]*b_routed[e_b,o])
// B=128, C_IN=C_OUT=64, HW=3136, fp32 I/O. Threshold 8.56e-2 = 8 bf16-ulps ->
// bf16 MFMA sanctioned. R5: mfma_f32_32x32x16_bf16, no LDS, no barriers.
// Wave = 32 out-ch x 128 px (4 tiles); block = 4 waves (2 o-tiles x 256 px).
// fp32 R2-R4 were VALU/spill-bound; MFMA cuts FMA time 21us -> 1.6us.

typedef __bf16 bf16x8 __attribute__((ext_vector_type(8)));
typedef float  f32x16 __attribute__((ext_vector_type(16)));

#define HW     3136
#define CIN    64
#define COUT   64
#define NTILES 98     // 3136 / 32 pixel-tiles
#define NGRP   13     // groups of 8 tiles; last group overlaps (rewrites same values)

__global__ __launch_bounds__(256, 4) void moe_mfma(
    const float* __restrict__ x,
    const float* __restrict__ weights,
    const int*   __restrict__ indices,
    const float* __restrict__ W_shared,
    const float* __restrict__ b_shared,
    const float* __restrict__ W_routed,
    const float* __restrict__ b_routed,
    float* __restrict__ out)
{
    const int bs   = blockIdx.y;          // sample
    const int wave = threadIdx.x >> 6;
    const int lane = threadIdx.x & 63;
    const int l5   = lane >> 5;           // 0/1 half-wave group
    const int l31  = lane & 31;

    const float wb = weights[bs];
    const int   e  = indices[bs];
    const int   ob = (wave >> 1) * 32;    // o-tile base (0 or 32)

    int tile0 = blockIdx.x * 8;
    if (tile0 > NTILES - 8) tile0 = NTILES - 8;   // overlap trick, deterministic
    const int px0 = (tile0 + (wave & 1) * 4) * 32;

    // ---- A fragments: W_eff[ob + l31][k], k = 16*ks + 8*l5 + j  (j=0..7) ----
    bf16x8 afrag[4];
    {
        const float* Ws = W_shared + (size_t)(ob + l31) * CIN + 8 * l5;
        const float* Wr = W_routed + ((size_t)e * COUT + ob + l31) * CIN + 8 * l5;
        #pragma unroll
        for (int ks = 0; ks < 4; ++ks) {
            float4 s0 = *(const float4*)(Ws + 16 * ks);
            float4 s1 = *(const float4*)(Ws + 16 * ks + 4);
            float4 r0 = *(const float4*)(Wr + 16 * ks);
            float4 r1 = *(const float4*)(Wr + 16 * ks + 4);
            float t[8];
            t[0] = s0.x + wb * r0.x;  t[1] = s0.y + wb * r0.y;
            t[2] = s0.z + wb * r0.z;  t[3] = s0.w + wb * r0.w;
            t[4] = s1.x + wb * r1.x;  t[5] = s1.y + wb * r1.y;
            t[6] = s1.z + wb * r1.z;  t[7] = s1.w + wb * r1.w;
            #pragma unroll
            for (int j = 0; j < 8; ++j) afrag[ks][j] = (__bf16)t[j];
        }
    }

    // ---- fused bias as accumulator init: reg r <-> row (r&3)+8*(r>>2)+4*l5 ----
    f32x16 biasv;
    #pragma unroll
    for (int g = 0; g < 4; ++g) {
        const int o4 = ob + 8 * g + 4 * l5;
        float4 s = *(const float4*)(b_shared + o4);
        float4 r = *(const float4*)(b_routed + e * COUT + o4);
        biasv[4 * g + 0] = s.x + wb * r.x;
        biasv[4 * g + 1] = s.y + wb * r.y;
        biasv[4 * g + 2] = s.z + wb * r.z;
        biasv[4 * g + 3] = s.w + wb * r.w;
    }

    const float* __restrict__ xs = x   + (size_t)bs * CIN  * HW;
    float*       __restrict__ os = out + (size_t)bs * COUT * HW;

    #pragma unroll 1
    for (int t = 0; t < 4; ++t) {
        const int px = px0 + t * 32 + l31;
        f32x16 acc = biasv;
        #pragma unroll
        for (int ks = 0; ks < 4; ++ks) {
            // B fragment: x[16*ks + 8*l5 + j][px]  (lanes 0-31 = 128B segments)
            const float* xp = xs + (size_t)(16 * ks + 8 * l5) * HW + px;
            float xv[8];
            #pragma unroll
            for (int j = 0; j < 8; ++j) xv[j] = xp[(size_t)j * HW];
            bf16x8 bfr;
            #pragma unroll
            for (int j = 0; j < 8; ++j) bfr[j] = (__bf16)xv[j];
            acc = __builtin_amdgcn_mfma_f32_32x32x16_bf16(afrag[ks], bfr, acc, 0, 0, 0);
        }
        // C store: verified layout col=l31, row=(r&3)+8*(r>>2)+4*l5
        #pragma unroll
        for (int r = 0; r < 16; ++r) {
            const int row = ob + (r & 3) + 8 * (r >> 2) + 4 * l5;
            os[(size_t)row * HW + px] = acc[r];
        }
    }
}

extern "C" void kernel_launch(void* const* d_in, const int* in_sizes, int n_in,
                              void* d_out, int out_size, void* d_ws, size_t ws_size,
                              hipStream_t stream) {
    const float* x        = (const float*)d_in[0];
    const float* weights  = (const float*)d_in[1];
    const int*   indices  = (const int*)  d_in[2];
    const float* W_shared = (const float*)d_in[3];
    const float* b_shared = (const float*)d_in[4];
    const float* W_routed = (const float*)d_in[5];
    const float* b_routed = (const float*)d_in[6];
    float* out = (float*)d_out;

    // 13 tile-groups x 128 samples; block = 4 waves = 2 o-tiles x 8 px-tiles
    moe_mfma<<<dim3(NGRP, 128), 256, 0, stream>>>(
        x, weights, indices, W_shared, b_shared, W_routed, b_routed, out);
}